// Round 5
// baseline (323.964 us; speedup 1.0000x reference)
//
#include <hip/hip_runtime.h>
#include <hip/hip_bf16.h>

#define CDIM 32
#define KCODES 4096
#define NROWS 65536
#define HW 4096
#define TPB 256
#define RTILE 64      // rows per block
#define KTILE 64      // codes per LDS tile
#define BETA 0.25f

// ---- workspace layout (bytes) ----
#define LOSS_OFF  0u
#define BIAS_OFF  256u
#define SCORE_OFF (BIAS_OFF + KCODES * 4u)
#define IDX_OFF   (SCORE_OFF + (unsigned)NROWS * 4u)

// bias[k] = -0.5 * ||e_k||^2
__global__ __launch_bounds__(256) void vq_bias(const float* __restrict__ table,
                                               float* __restrict__ bias) {
    int k = blockIdx.x * 256 + threadIdx.x;
    if (k >= KCODES) return;
    const float4* row = (const float4*)(table + (size_t)k * CDIM);
    float s = 0.f;
#pragma unroll
    for (int i = 0; i < CDIM / 4; ++i) {
        float4 v = row[i];
        s = fmaf(v.x, v.x, s);
        s = fmaf(v.y, v.y, s);
        s = fmaf(v.z, v.z, s);
        s = fmaf(v.w, v.w, s);
    }
    bias[k] = -0.5f * s;
}

// Register-tiled scoring: block = 64 rows x all 4096 codes, thread = 4 rows x 4 codes.
__global__ __launch_bounds__(TPB, 4) void vq_main(const float* __restrict__ z,
                                                  const float* __restrict__ table,
                                                  const float* __restrict__ bias,
                                                  float* __restrict__ scores,
                                                  int* __restrict__ idxs) {
    __shared__ __align__(16) float zt[CDIM][RTILE];   // 8 KB, z transposed-by-construction
    __shared__ __align__(16) float et[CDIM][KTILE];   // 8 KB, codes transposed
    __shared__ __align__(16) float blds[KTILE];

    const int t  = threadIdx.x;
    const int tx = t & 15;          // code-slot group
    const int ty = t >> 4;          // row group (0..15)
    const int row0 = blockIdx.x * RTILE;
    const int b   = row0 >> 12;     // 4096 rows per batch image
    const int hw0 = row0 & (HW - 1);
    const float* zb = z + (size_t)b * CDIM * HW + hw0;

    // stage z tile: global [c][hw] is already the layout we want
    {
        int c = t >> 4, q = t & 15;
        float4 v0 = *(const float4*)(zb + (size_t)c * HW + q * 4);
        *(float4*)&zt[c][q * 4] = v0;
        float4 v1 = *(const float4*)(zb + (size_t)(c + 16) * HW + q * 4);
        *(float4*)&zt[c + 16][q * 4] = v1;
    }

    float best[4] = {-1e30f, -1e30f, -1e30f, -1e30f};
    int   bi[4]   = {0, 0, 0, 0};

    for (int k0 = 0; k0 < KCODES; k0 += KTILE) {
        __syncthreads();
        {   // stage 64 codes, transposed: et[c][k]
            int k = t & 63, c4 = t >> 6;                 // c4 in 0..3, and c4+4
            const float* er = table + (size_t)(k0 + k) * CDIM;
            float4 v = *(const float4*)(er + c4 * 4);
            et[c4 * 4 + 0][k] = v.x;
            et[c4 * 4 + 1][k] = v.y;
            et[c4 * 4 + 2][k] = v.z;
            et[c4 * 4 + 3][k] = v.w;
            float4 w = *(const float4*)(er + (c4 + 4) * 4);
            et[(c4 + 4) * 4 + 0][k] = w.x;
            et[(c4 + 4) * 4 + 1][k] = w.y;
            et[(c4 + 4) * 4 + 2][k] = w.z;
            et[(c4 + 4) * 4 + 3][k] = w.w;
            if (t < 16) *(float4*)&blds[t * 4] = *(const float4*)(bias + k0 + t * 4);
        }
        __syncthreads();

        float4 bv = *(const float4*)&blds[tx * 4];
        float acc[4][4];                                  // [row j][code i]
#pragma unroll
        for (int j = 0; j < 4; ++j) {
            acc[j][0] = bv.x; acc[j][1] = bv.y; acc[j][2] = bv.z; acc[j][3] = bv.w;
        }

#pragma unroll
        for (int c = 0; c < CDIM; ++c) {
            float4 zv = *(const float4*)&zt[c][ty * 4];
            float4 ev = *(const float4*)&et[c][tx * 4];
            acc[0][0] = fmaf(zv.x, ev.x, acc[0][0]);
            acc[0][1] = fmaf(zv.x, ev.y, acc[0][1]);
            acc[0][2] = fmaf(zv.x, ev.z, acc[0][2]);
            acc[0][3] = fmaf(zv.x, ev.w, acc[0][3]);
            acc[1][0] = fmaf(zv.y, ev.x, acc[1][0]);
            acc[1][1] = fmaf(zv.y, ev.y, acc[1][1]);
            acc[1][2] = fmaf(zv.y, ev.z, acc[1][2]);
            acc[1][3] = fmaf(zv.y, ev.w, acc[1][3]);
            acc[2][0] = fmaf(zv.z, ev.x, acc[2][0]);
            acc[2][1] = fmaf(zv.z, ev.y, acc[2][1]);
            acc[2][2] = fmaf(zv.z, ev.z, acc[2][2]);
            acc[2][3] = fmaf(zv.z, ev.w, acc[2][3]);
            acc[3][0] = fmaf(zv.w, ev.x, acc[3][0]);
            acc[3][1] = fmaf(zv.w, ev.y, acc[3][1]);
            acc[3][2] = fmaf(zv.w, ev.z, acc[3][2]);
            acc[3][3] = fmaf(zv.w, ev.w, acc[3][3]);
        }

#pragma unroll
        for (int j = 0; j < 4; ++j) {
#pragma unroll
            for (int i = 0; i < 4; ++i) {
                int k = k0 + tx * 4 + i;                  // ascending k overall
                if (acc[j][i] > best[j]) { best[j] = acc[j][i]; bi[j] = k; } // strict >: first wins
            }
        }
    }

    // merge across the 16 tx-lanes of each row group (lanes differ in bits 0..3)
#pragma unroll
    for (int j = 0; j < 4; ++j) {
        float s = best[j];
        int   i = bi[j];
#pragma unroll
        for (int m = 1; m <= 8; m <<= 1) {
            float s2 = __shfl_xor(s, m);
            int   i2 = __shfl_xor(i, m);
            if (s2 > s || (s2 == s && i2 < i)) { s = s2; i = i2; }  // tie -> lowest k
        }
        if (tx == 0) {
            int n = row0 + ty * 4 + j;
            scores[n] = s;
            idxs[n]   = i;
        }
    }
}

__global__ __launch_bounds__(256) void vq_combine(const float* __restrict__ scores,
                                                  const int* __restrict__ idxs,
                                                  const float* __restrict__ z,
                                                  const float* __restrict__ table,
                                                  float* __restrict__ out_zq,
                                                  float* __restrict__ out_idx,
                                                  float* __restrict__ loss) {
    const int n = blockIdx.x * 256 + threadIdx.x;
    const int bi = idxs[n];
    const float best = scores[n];
    const int b = n >> 12;
    const int hw = n & (HW - 1);

    const float* zb = z + (size_t)b * CDIM * HW + hw;
    float z2 = 0.f;
#pragma unroll
    for (int c = 0; c < CDIM; ++c) {
        float v = zb[(size_t)c * HW];
        z2 = fmaf(v, v, z2);
    }

    out_idx[n] = (float)bi;

    const float4* trow = (const float4*)(table + (size_t)bi * CDIM);
    float* o = out_zq + (size_t)b * CDIM * HW + hw;
#pragma unroll
    for (int c4 = 0; c4 < CDIM / 4; ++c4) {
        float4 v = trow[c4];
        o[(size_t)(c4 * 4 + 0) * HW] = v.x;
        o[(size_t)(c4 * 4 + 1) * HW] = v.y;
        o[(size_t)(c4 * 4 + 2) * HW] = v.z;
        o[(size_t)(c4 * 4 + 3) * HW] = v.w;
    }

    // d = ||z||^2 - 2*(z.e - 0.5||e||^2) = ||z - e||^2
    float d = fmaxf(z2 - 2.0f * best, 0.0f);
#pragma unroll
    for (int off = 32; off; off >>= 1) d += __shfl_down(d, off);
    if ((threadIdx.x & 63) == 0) atomicAdd(loss, d);
}

__global__ void vq_finalize(const float* __restrict__ loss,
                            float* __restrict__ out_loss) {
    out_loss[0] = loss[0] * (1.0f + BETA) / (float)((size_t)NROWS * CDIM);
}

extern "C" void kernel_launch(void* const* d_in, const int* in_sizes, int n_in,
                              void* d_out, int out_size, void* d_ws, size_t ws_size,
                              hipStream_t stream) {
    const float* z     = (const float*)d_in[0];
    const float* table = (const float*)d_in[1];

    char* ws = (char*)d_ws;
    float* loss   = (float*)(ws + LOSS_OFF);
    float* bias   = (float*)(ws + BIAS_OFF);
    float* scores = (float*)(ws + SCORE_OFF);
    int*   idxs   = (int*)(ws + IDX_OFF);

    float* out_zq   = (float*)d_out;
    float* out_idx  = out_zq + (size_t)NROWS * CDIM;
    float* out_loss = out_idx + NROWS;

    hipMemsetAsync(loss, 0, sizeof(float), stream);

    vq_bias<<<KCODES / 256, 256, 0, stream>>>(table, bias);
    vq_main<<<NROWS / RTILE, TPB, 0, stream>>>(z, table, bias, scores, idxs);
    vq_combine<<<NROWS / 256, 256, 0, stream>>>(scores, idxs, z, table,
                                                out_zq, out_idx, loss);
    vq_finalize<<<1, 1, 0, stream>>>(loss, out_loss);
}

// Round 10
// 285.379 us; speedup vs baseline: 1.1352x; 1.1352x over previous
//
#include <hip/hip_runtime.h>
#include <hip/hip_bf16.h>

#define CDIM 32
#define KCODES 4096
#define NROWS 65536
#define HW 4096
#define KP 8
#define KSLICE (KCODES / KP)   // 512 codes per partition
#define TPB 256
#define BETA 0.25f

// ---- workspace layout (bytes) ----
#define LOSS_OFF  0u
#define BIAS_OFF  256u
#define SCORE_OFF (BIAS_OFF + KCODES * 4u)
#define IDX_OFF   (SCORE_OFF + (unsigned)KP * NROWS * 4u)

// bias[k] = -0.5 * ||e_k||^2
__global__ __launch_bounds__(256) void vq_bias(const float* __restrict__ table,
                                               float* __restrict__ bias) {
    int k = blockIdx.x * 256 + threadIdx.x;
    if (k >= KCODES) return;
    const float4* row = (const float4*)(table + (size_t)k * CDIM);
    float s = 0.f;
#pragma unroll
    for (int i = 0; i < CDIM / 4; ++i) {
        float4 v = row[i];
        s = fmaf(v.x, v.x, s);
        s = fmaf(v.y, v.y, s);
        s = fmaf(v.z, v.z, s);
        s = fmaf(v.w, v.w, s);
    }
    bias[k] = -0.5f * s;
}

// Scalar-operand scoring: e-rows and bias come through the scalar pipe (SGPRs,
// wave-uniform), z lives in VGPRs. Inner loop has NO LDS and NO VMEM.
// Each thread owns 2 consecutive rows; each block = 512 rows x 512 codes.
__global__ __launch_bounds__(TPB, 2) void vq_main(const float* __restrict__ z,
                                                  const float* __restrict__ table,
                                                  const float* __restrict__ bias,
                                                  float* __restrict__ scores,
                                                  int* __restrict__ idxs) {
    const int t    = threadIdx.x;
    const int kp   = blockIdx.y;
    const int row0 = blockIdx.x * (TPB * 2);
    const int n0   = row0 + t * 2;          // rows n0, n0+1
    const int b    = n0 >> 12;
    const int hw   = n0 & (HW - 1);
    const float* zb = z + (size_t)b * CDIM * HW + hw;

    // 2 z-rows in registers (64 VGPR), coalesced float2 loads
    float z0[CDIM], z1[CDIM];
#pragma unroll
    for (int c = 0; c < CDIM; ++c) {
        float2 v = *(const float2*)(zb + (size_t)c * HW);
        z0[c] = v.x;
        z1[c] = v.y;
    }

    float best0 = -1e30f, best1 = -1e30f;
    int bi0 = 0, bi1 = 0;

    const int kbeg = kp * KSLICE;
    const int kend = kbeg + KSLICE;
#pragma unroll 2
    for (int k = kbeg; k < kend; ++k) {
        const float* er = table + (size_t)k * CDIM;   // uniform -> s_load
        float a0 = bias[k];                           // uniform -> s_load
        float a1 = a0;
#pragma unroll
        for (int c = 0; c < CDIM; ++c) {
            float e = er[c];                          // SGPR operand
            a0 = fmaf(z0[c], e, a0);
            a1 = fmaf(z1[c], e, a1);
        }
        if (a0 > best0) { best0 = a0; bi0 = k; }      // strict >: first (lowest k) wins
        if (a1 > best1) { best1 = a1; bi1 = k; }
    }

    *(float2*)(scores + (size_t)kp * NROWS + n0) = make_float2(best0, best1);
    *(int2*)(idxs + (size_t)kp * NROWS + n0)     = make_int2(bi0, bi1);
}

__global__ __launch_bounds__(256) void vq_combine(const float* __restrict__ scores,
                                                  const int* __restrict__ idxs,
                                                  const float* __restrict__ z,
                                                  const float* __restrict__ table,
                                                  float* __restrict__ out_zq,
                                                  float* __restrict__ out_idx,
                                                  float* __restrict__ loss) {
    const int n = blockIdx.x * 256 + threadIdx.x;
    float best = -1e30f;
    int bi = 0;
#pragma unroll
    for (int kp = 0; kp < KP; ++kp) {   // ascending partitions => lowest k wins ties
        float s = scores[(size_t)kp * NROWS + n];
        int   i = idxs[(size_t)kp * NROWS + n];
        if (s > best) { best = s; bi = i; }
    }

    const int b  = n >> 12;
    const int hw = n & (HW - 1);

    const float* zbp = z + (size_t)b * CDIM * HW + hw;
    float z2 = 0.f;
#pragma unroll
    for (int c = 0; c < CDIM; ++c) {
        float v = zbp[(size_t)c * HW];
        z2 = fmaf(v, v, z2);
    }

    out_idx[n] = (float)bi;

    const float4* trow = (const float4*)(table + (size_t)bi * CDIM);
    float* o = out_zq + (size_t)b * CDIM * HW + hw;
#pragma unroll
    for (int c4 = 0; c4 < CDIM / 4; ++c4) {
        float4 v = trow[c4];
        o[(size_t)(c4 * 4 + 0) * HW] = v.x;
        o[(size_t)(c4 * 4 + 1) * HW] = v.y;
        o[(size_t)(c4 * 4 + 2) * HW] = v.z;
        o[(size_t)(c4 * 4 + 3) * HW] = v.w;
    }

    // d = ||z||^2 - 2*(z.e - 0.5||e||^2) = ||z - e||^2
    float d = fmaxf(z2 - 2.0f * best, 0.0f);
#pragma unroll
    for (int off = 32; off; off >>= 1) d += __shfl_down(d, off);
    if ((threadIdx.x & 63) == 0) atomicAdd(loss, d);
}

__global__ void vq_finalize(const float* __restrict__ loss,
                            float* __restrict__ out_loss) {
    out_loss[0] = loss[0] * (1.0f + BETA) / (float)((size_t)NROWS * CDIM);
}

extern "C" void kernel_launch(void* const* d_in, const int* in_sizes, int n_in,
                              void* d_out, int out_size, void* d_ws, size_t ws_size,
                              hipStream_t stream) {
    const float* z     = (const float*)d_in[0];
    const float* table = (const float*)d_in[1];

    char* ws = (char*)d_ws;
    float* loss   = (float*)(ws + LOSS_OFF);
    float* bias   = (float*)(ws + BIAS_OFF);
    float* scores = (float*)(ws + SCORE_OFF);
    int*   idxs   = (int*)(ws + IDX_OFF);

    float* out_zq   = (float*)d_out;
    float* out_idx  = out_zq + (size_t)NROWS * CDIM;
    float* out_loss = out_idx + NROWS;

    hipMemsetAsync(loss, 0, sizeof(float), stream);

    vq_bias<<<KCODES / 256, 256, 0, stream>>>(table, bias);

    dim3 grid(NROWS / (TPB * 2), KP);   // 128 x 8 = 1024 blocks, 4 waves each
    vq_main<<<grid, TPB, 0, stream>>>(z, table, bias, scores, idxs);

    vq_combine<<<NROWS / 256, 256, 0, stream>>>(scores, idxs, z, table,
                                                out_zq, out_idx, loss);
    vq_finalize<<<1, 1, 0, stream>>>(loss, out_loss);
}